// Round 8
// baseline (470.695 us; speedup 1.0000x reference)
//
#include <hip/hip_runtime.h>
#include <hip/hip_bf16.h>

#define BB 4
#define NH 8
#define HD 64
#define CC 512
#define LL 2048
#define KK 1536   // C*3, K index = t*512 + ci
#define LPAD 2050 // padded rows of xT: row 0 and row 2049 are zeros

typedef float f32x4 __attribute__((ext_vector_type(4)));
typedef short bf16x8 __attribute__((ext_vector_type(8)));

static __device__ __forceinline__ ushort f2bf(float f) {
  union { float f; unsigned u; } v; v.f = f;
  unsigned r = v.u + 0x7fffu + ((v.u >> 16) & 1u);   // RNE
  return (ushort)(r >> 16);
}
static __device__ __forceinline__ float bf2f(ushort u) {
  union { unsigned u; float f; } v; v.u = ((unsigned)u) << 16;
  return v.f;
}
static __device__ __forceinline__ void gload16(const ushort* g, ushort* l) {
  __builtin_amdgcn_global_load_lds((const __attribute__((address_space(1))) void*)g,
                                   (__attribute__((address_space(3))) void*)l, 16, 0, 0);
}

// ---------------------------------------------------------------------------
// Weight prep: W[co][ci][t] fp32 -> W'[co][t*512+ci] bf16, for all 4 convs.
// ---------------------------------------------------------------------------
__global__ void prep_w(const float* __restrict__ w0, const float* __restrict__ w1,
                       const float* __restrict__ w2, const float* __restrict__ w3,
                       ushort* __restrict__ out)
{
  int i = blockIdx.x * 256 + threadIdx.x;
  const int per = CC * KK;
  if (i >= 4 * per) return;
  int cidx = i / per;
  int rem  = i - cidx * per;
  int co   = rem / KK;
  int kk   = rem - co * KK;
  int t = kk >> 9, ci = kk & 511;
  const float* w = (cidx == 0) ? w0 : (cidx == 1) ? w1 : (cidx == 2) ? w2 : w3;
  out[i] = f2bf(w[((size_t)co * CC + ci) * 3 + t]);
}

// ---------------------------------------------------------------------------
// Transpose+cast body: xb[c][l] fp32 -> ob[l+1][c] bf16, zero halo rows.
// ---------------------------------------------------------------------------
__device__ __forceinline__ void transpose_body(const float* __restrict__ xb,
                                               ushort* __restrict__ ob)
{
  const int c0 = blockIdx.y * 64;
  const int l0 = blockIdx.x * 64;
  const int tid = threadIdx.x;
  __shared__ ushort T[64 * 72];
  {
    const int rr = tid >> 4;      // 0..15
    const int f4 = tid & 15;      // 0..15
#pragma unroll
    for (int it = 0; it < 4; ++it) {
      const int cc = rr + it * 16;
      ushort s[4];
      float4 vv = *(const float4*)(xb + (size_t)(c0 + cc) * LL + l0 + f4 * 4);
      s[0] = f2bf(vv.x); s[1] = f2bf(vv.y); s[2] = f2bf(vv.z); s[3] = f2bf(vv.w);
      *(ushort4*)&T[cc * 72 + f4 * 4] = *(ushort4*)s;
    }
  }
  __syncthreads();
  {
    const int lr = tid >> 3;     // 0..31
    const int ch = tid & 7;      // 0..7
#pragma unroll
    for (int it = 0; it < 2; ++it) {
      const int ll = lr + it * 32;
      ushort tmp[8];
#pragma unroll
      for (int e = 0; e < 8; ++e) tmp[e] = T[(ch * 8 + e) * 72 + ll];
      *(uint4*)(ob + (size_t)(l0 + ll + 1) * CC + c0 + ch * 8) = *(uint4*)tmp;
    }
  }
  if (blockIdx.x == 0 && tid < 8) {
    uint4 z4 = make_uint4(0, 0, 0, 0);
    *(uint4*)(ob + c0 + tid * 8) = z4;
  }
  if (blockIdx.x == (LL / 64 - 1) && tid >= 248) {
    uint4 z4 = make_uint4(0, 0, 0, 0);
    *(uint4*)(ob + (size_t)(LPAD - 1) * CC + c0 + (tid - 248) * 8) = z4;
  }
}

__global__ __launch_bounds__(256, 4)
void transpose_k(const float* __restrict__ in, ushort* __restrict__ outT)
{
  const int b = blockIdx.z;
  transpose_body(in + (size_t)b * CC * LL, outT + (size_t)b * (LPAD * CC));
}

__global__ __launch_bounds__(256, 4)
void transpose3_k(const float* __restrict__ q, const float* __restrict__ k,
                  const float* __restrict__ v, ushort* __restrict__ xq,
                  ushort* __restrict__ xk, ushort* __restrict__ xv)
{
  const int z = blockIdx.z;
  const int b = z & 3, var = z >> 2;
  const float* in = (var == 0) ? q : (var == 1) ? k : v;
  ushort* out = (var == 0) ? xq : (var == 1) ? xk : xv;
  transpose_body(in + (size_t)b * CC * LL, out + (size_t)b * (LPAD * CC));
}

// ---------------------------------------------------------------------------
// conv1d(k=3,same) as implicit GEMM — ROUND-6 PROVEN SHAPE: M=128 x N=128,
// BK=64, single-buffer 2-barrier, 8x global_load_lds(16B)/thread, XOR chunk
// swizzle on the global fetch address, 32 MFMA/wave per iter.
// mode 0: heads [b][h][x][d] bf16 (q,k) | 1: heads-T [b][h][d][x] bf16 (v)
// mode 2: [b][co][l] fp32 (final fc)
// ---------------------------------------------------------------------------
__device__ __forceinline__ void conv_body(const ushort* __restrict__ xb,
                                          const ushort* __restrict__ Wt,
                                          const float* __restrict__ bias,
                                          void* __restrict__ outp, int mode, int b)
{
  const int co0 = blockIdx.y * 128;
  const int l0  = blockIdx.x * 128;
  const int tid = threadIdx.x;
  const int lane = tid & 63;
  const int w    = tid >> 6;
  const int col  = lane & 15, quad = lane >> 4;

  __shared__ ushort Asl[128 * 64];   // 16 KB
  __shared__ ushort Bsl[128 * 64];   // 16 KB

  const int sr = tid >> 3;                 // 0..31
  const int g8 = ((tid & 7) ^ (sr & 7)) * 8;
  const ushort* ag  = Wt + (size_t)(co0 + sr) * KK + g8;
  const ushort* bg  = xb + (size_t)(l0 + sr) * CC + g8;
  ushort* alds = &Asl[tid * 8];
  ushort* blds = &Bsl[tid * 8];

  f32x4 acc[4][4] = {};
  const int wm = (w & 1) * 64;
  const int wn = (w >> 1) * 64;
  const int c7 = col & 7;

  for (int k0 = 0; k0 < KK; k0 += 64) {
#pragma unroll
    for (int r2 = 0; r2 < 4; ++r2) {
      gload16(ag + (size_t)(r2 * 32) * KK + k0, alds + r2 * 2048);
      gload16(bg + (size_t)(r2 * 32) * CC + k0, blds + r2 * 2048);
    }
    __syncthreads();
#pragma unroll
    for (int kk = 0; kk < 2; ++kk) {
      bf16x8 af[4], bfr[4];
#pragma unroll
      for (int i = 0; i < 4; ++i)
        af[i] = *(const bf16x8*)&Asl[(wm + i * 16 + col) * 64 + (((kk * 4 + quad) ^ c7) * 8)];
#pragma unroll
      for (int j = 0; j < 4; ++j)
        bfr[j] = *(const bf16x8*)&Bsl[(wn + j * 16 + col) * 64 + (((kk * 4 + quad) ^ c7) * 8)];
#pragma unroll
      for (int i = 0; i < 4; ++i)
#pragma unroll
        for (int j = 0; j < 4; ++j)
          acc[i][j] = __builtin_amdgcn_mfma_f32_16x16x32_bf16(af[i], bfr[j], acc[i][j], 0, 0, 0);
    }
    __syncthreads();
  }

  // epilogue: C/D layout row = quad*4+r (co), col = lane&15 (l)
#pragma unroll
  for (int i = 0; i < 4; ++i) {
#pragma unroll
    for (int r = 0; r < 4; ++r) {
      const int co = co0 + wm + i * 16 + quad * 4 + r;
      const float bi = bias[co];
#pragma unroll
      for (int j = 0; j < 4; ++j) {
        const int l = l0 + wn + j * 16 + col;
        const float y = acc[i][j][r] + bi;
        if (mode == 0) {
          const int xx = (co << 2) + (l >> 9);
          const int hh = (l >> 6) & 7;
          const int dd = l & 63;
          ((ushort*)outp)[((size_t)(b * NH + hh) * LL + xx) * HD + dd] = f2bf(y);
        } else if (mode == 1) {
          const int xx = (co << 2) + (l >> 9);
          const int hh = (l >> 6) & 7;
          const int dd = l & 63;
          ((ushort*)outp)[((size_t)(b * NH + hh) * HD + dd) * LL + xx] = f2bf(y);
        } else {
          ((float*)outp)[(size_t)(b * CC + co) * LL + l] = y;
        }
      }
    }
  }
}

__global__ __launch_bounds__(256, 3)
void conv_k(const ushort* __restrict__ xT, const ushort* __restrict__ Wt,
            const float* __restrict__ bias, void* __restrict__ outp, int mode)
{
  const int b = blockIdx.z;
  conv_body(xT + (size_t)b * (LPAD * CC), Wt, bias, outp, mode, b);
}

__global__ __launch_bounds__(256, 3)
void conv3_k(const ushort* __restrict__ xq, const ushort* __restrict__ xk,
             const ushort* __restrict__ xv, const ushort* __restrict__ Wt,
             const float* __restrict__ b0, const float* __restrict__ b1,
             const float* __restrict__ b2, ushort* __restrict__ o0,
             ushort* __restrict__ o1, ushort* __restrict__ o2)
{
  const int z = blockIdx.z;
  const int b = z & 3, var = z >> 2;
  const ushort* xT = (var == 0) ? xq : (var == 1) ? xk : xv;
  const float* bias = (var == 0) ? b0 : (var == 1) ? b1 : b2;
  ushort* outp = (var == 0) ? o0 : (var == 1) ? o1 : o2;
  conv_body(xT + (size_t)b * (LPAD * CC), Wt + (size_t)var * CC * KK, bias, outp,
            (var == 2) ? 1 : 0, b);
}

// ---------------------------------------------------------------------------
// Attention v7: v6 core (4 waves x 32 Q-rows, dbuf LDS K/V, S^T trick, 1
// barrier/y-tile, ones-MFMA denom) + 2-WAY BLOCK-LEVEL y-SPLIT:
// grid 1024 (vs 512) so LDS 50 KB (Ps stride 72) gives 3 blocks/CU = 12
// waves.  Partials additive (no max-subtraction).  Combine protocol:
// each block writes bf16 O-partials + f32 denoms to dead ws, __threadfence
// (agent release) + device-scope atomicAdd on a per-pair counter; the SECOND
// arriver reads the peer's partials, combines, normalizes, scatters to the
// padded-transposed obT.  Both splits of a pair land on the same XCD by the
// swizzle (perf); correctness relies only on fence+atomic (G16 pattern).
// ---------------------------------------------------------------------------
__global__ __launch_bounds__(256, 3)
void attn_k(const ushort* __restrict__ qh, const ushort* __restrict__ kh,
            const ushort* __restrict__ vt, ushort* __restrict__ Pp,
            float* __restrict__ Dp, int* __restrict__ cnt,
            ushort* __restrict__ obT)
{
  const int id   = blockIdx.x;       // 0..1023
  const int xcd  = id & 7;
  const int slot = id >> 3;          // 0..127
  const int bh   = xcd * 4 + (slot >> 5);
  const int xt   = (slot >> 1) & 15;
  const int split = slot & 1;
  const int x0   = xt * 128;
  const int pair = bh * 16 + xt;
  const int b = bh >> 3, h = bh & 7;
  const int tid = threadIdx.x, lane = tid & 63, wv = tid >> 6;
  const int col = lane & 15, quad = lane >> 4;
  const int wx = wv * 32;            // wave-private Q rows / P rows
  const int c7 = col & 7;

  __shared__ ushort Kv[2][8192];     // [buf][ K 64x64 | V^T 64x64 ]  32 KB
  __shared__ ushort Ps[128 * 72];    // 18 KB  (P[x][y], stride 72)
  __shared__ int iswin;

  const ushort* Qg = qh + (size_t)bh * (LL * HD);
  const ushort* Kg = kh + (size_t)bh * (LL * HD);
  const ushort* Vg = vt + (size_t)bh * (HD * LL);
  ushort* ob = obT + (size_t)b * (LPAD * CC);

  const int sr = tid >> 3;                 // 0..31
  const int g8 = ((tid & 7) ^ (sr & 7)) * 8;

  // Q fragments (lane&15 = x-row, k = quad*8+j) — valid as A or B operand
  bf16x8 aq[2][2];
#pragma unroll
  for (int i = 0; i < 2; ++i)
#pragma unroll
    for (int kk = 0; kk < 2; ++kk)
      aq[i][kk] = *(const bf16x8*)(Qg + (size_t)(x0 + wx + i * 16 + col) * HD + kk * 32 + quad * 8);

  const short one = (short)0x3F80;  // bf16 1.0
  const bf16x8 ones = {one, one, one, one, one, one, one, one};

  f32x4 oacc[2][4] = {};
  f32x4 dacc[2] = {};

  const int ybeg = split * 16, yend = ybeg + 16;   // 16 y-tiles of 64
  // prefetch first tile into buf 0 (ybeg even -> cur starts at 0)
  {
    const int y0 = ybeg * 64;
    ushort* kb = &Kv[0][tid * 8];
    gload16(Kg + (size_t)(y0 + sr) * HD + g8, kb);
    gload16(Kg + (size_t)(y0 + 32 + sr) * HD + g8, kb + 2048);
    gload16(Vg + (size_t)sr * LL + y0 + g8, kb + 4096);
    gload16(Vg + (size_t)(32 + sr) * LL + y0 + g8, kb + 6144);
  }

  for (int yt = ybeg; yt < yend; ++yt) {
    const int cur = yt & 1;
    __syncthreads();
    if (yt + 1 < yend) {
      const int y1 = (yt + 1) * 64;
      ushort* kb = &Kv[1 - cur][tid * 8];
      gload16(Kg + (size_t)(y1 + sr) * HD + g8, kb);
      gload16(Kg + (size_t)(y1 + 32 + sr) * HD + g8, kb + 2048);
      gload16(Vg + (size_t)sr * LL + y1 + g8, kb + 4096);
      gload16(Vg + (size_t)(32 + sr) * LL + y1 + g8, kb + 6144);
    }
    const ushort* Kb = &Kv[cur][0];
    const ushort* Vb = &Kv[cur][4096];

    // S^T = K Q^T : C rows (quad*4+r) = y-local, cols = x-local
    f32x4 sacc[4][2] = {};
#pragma unroll
    for (int kk = 0; kk < 2; ++kk)
#pragma unroll
      for (int j = 0; j < 4; ++j) {
        bf16x8 bk = *(const bf16x8*)&Kb[(j * 16 + col) * 64 + (((kk * 4 + quad) ^ c7) * 8)];
        sacc[j][0] = __builtin_amdgcn_mfma_f32_16x16x32_bf16(bk, aq[0][kk], sacc[j][0], 0, 0, 0);
        sacc[j][1] = __builtin_amdgcn_mfma_f32_16x16x32_bf16(bk, aq[1][kk], sacc[j][1], 0, 0, 0);
      }
    // exp + pack 4 consecutive-y bf16 -> one ds_write_b64 per (j,i)
#pragma unroll
    for (int j = 0; j < 4; ++j)
#pragma unroll
      for (int i = 0; i < 2; ++i) {
        union { __hip_bfloat162 h[2]; uint2 u; } pk;
        pk.h[0] = __float22bfloat162_rn(make_float2(__expf(sacc[j][i][0] * 0.015625f),
                                                   __expf(sacc[j][i][1] * 0.015625f)));
        pk.h[1] = __float22bfloat162_rn(make_float2(__expf(sacc[j][i][2] * 0.015625f),
                                                   __expf(sacc[j][i][3] * 0.015625f)));
        *(uint2*)&Ps[(wx + i * 16 + col) * 72 + j * 16 + quad * 4] = pk.u;
      }
    // O += P V ; denom += P * ones
#pragma unroll
    for (int kk = 0; kk < 2; ++kk) {
      bf16x8 ap0 = *(const bf16x8*)&Ps[(wx + col) * 72 + kk * 32 + quad * 8];
      bf16x8 ap1 = *(const bf16x8*)&Ps[(wx + 16 + col) * 72 + kk * 32 + quad * 8];
      dacc[0] = __builtin_amdgcn_mfma_f32_16x16x32_bf16(ap0, ones, dacc[0], 0, 0, 0);
      dacc[1] = __builtin_amdgcn_mfma_f32_16x16x32_bf16(ap1, ones, dacc[1], 0, 0, 0);
#pragma unroll
      for (int j = 0; j < 4; ++j) {
        bf16x8 bv = *(const bf16x8*)&Vb[(j * 16 + col) * 64 + (((kk * 4 + quad) ^ c7) * 8)];
        oacc[0][j] = __builtin_amdgcn_mfma_f32_16x16x32_bf16(ap0, bv, oacc[0][j], 0, 0, 0);
        oacc[1][j] = __builtin_amdgcn_mfma_f32_16x16x32_bf16(ap1, bv, oacc[1][j], 0, 0, 0);
      }
    }
  }

  // ---- write my partials (bf16 O, f32 denom) ----
  ushort* myP = Pp + (size_t)(pair * 2 + split) * (128 * 64);
  float*  myD = Dp + (size_t)(pair * 2 + split) * 128;
#pragma unroll
  for (int i = 0; i < 2; ++i)
#pragma unroll
    for (int r = 0; r < 4; ++r) {
      const int row = wx + i * 16 + quad * 4 + r;
#pragma unroll
      for (int j = 0; j < 4; ++j)
        myP[row * 64 + j * 16 + col] = f2bf(oacc[i][j][r]);
      if (col == 0) myD[row] = dacc[i][r];
    }
  __threadfence();          // agent-scope release of my stores
  __syncthreads();          // all threads' stores fenced before the atomic
  if (tid == 0) iswin = (atomicAdd(cnt + pair, 1) == 1);
  __syncthreads();

  // halo rows for obT (never touched by scatter; idempotent zero writes)
  if (xt == 0 && tid < 128) {
    const int rw = tid >> 6;
    const int cc = h * 64 + (tid & 63);
    ob[(size_t)(rw ? (LPAD - 1) : 0) * CC + cc] = 0;
  }

  if (!iswin) return;
  __threadfence();          // acquire before reading peer partials

  const ushort* pP = Pp + (size_t)(pair * 2 + (1 - split)) * (128 * 64);
  const float*  pD = Dp + (size_t)(pair * 2 + (1 - split)) * 128;
#pragma unroll
  for (int i = 0; i < 2; ++i) {
#pragma unroll
    for (int r = 0; r < 4; ++r) {
      const int row = wx + i * 16 + quad * 4 + r;
      const int xg = x0 + row;
      const float inv = 1.f / (dacc[i][r] + pD[row]);
#pragma unroll
      for (int j = 0; j < 4; ++j) {
        const float ov = oacc[i][j][r] + bf2f(pP[row * 64 + j * 16 + col]);
        const int d = j * 16 + col;
        const int flat = xg * 512 + h * 64 + d;
        const int c = flat >> 11, l = flat & 2047;
        ob[(size_t)(l + 1) * CC + c] = f2bf(ov * inv);
      }
    }
  }
}

// ---------------------------------------------------------------------------
// Attention fallback (v6, grid 512) for the sequential ws layout.
// ---------------------------------------------------------------------------
__global__ __launch_bounds__(256, 2)
void attn1_k(const ushort* __restrict__ qh, const ushort* __restrict__ kh,
             const ushort* __restrict__ vt, ushort* __restrict__ obT)
{
  const int id   = blockIdx.x;
  const int xcd  = id & 7;
  const int slot = id >> 3;
  const int bh   = xcd * 4 + (slot >> 4);
  const int x0   = (slot & 15) * 128;
  const int b = bh >> 3, h = bh & 7;
  const int tid = threadIdx.x, lane = tid & 63, wv = tid >> 6;
  const int col = lane & 15, quad = lane >> 4;
  const int wx = wv * 32;
  const int c7 = col & 7;

  __shared__ ushort Kv[2][8192];
  __shared__ ushort Ps[128 * 88];

  const ushort* Qg = qh + (size_t)bh * (LL * HD);
  const ushort* Kg = kh + (size_t)bh * (LL * HD);
  const ushort* Vg = vt + (size_t)bh * (HD * LL);
  ushort* ob = obT + (size_t)b * (LPAD * CC);

  const int sr = tid >> 3;
  const int g8 = ((tid & 7) ^ (sr & 7)) * 8;

  bf16x8 aq[2][2];
#pragma unroll
  for (int i = 0; i < 2; ++i)
#pragma unroll
    for (int kk = 0; kk < 2; ++kk)
      aq[i][kk] = *(const bf16x8*)(Qg + (size_t)(x0 + wx + i * 16 + col) * HD + kk * 32 + quad * 8);

  const short one = (short)0x3F80;
  const bf16x8 ones = {one, one, one, one, one, one, one, one};

  f32x4 oacc[2][4] = {};
  f32x4 dacc[2] = {};

  {
    ushort* kb = &Kv[0][tid * 8];
    gload16(Kg + (size_t)sr * HD + g8, kb);
    gload16(Kg + (size_t)(32 + sr) * HD + g8, kb + 2048);
    gload16(Vg + (size_t)sr * LL + g8, kb + 4096);
    gload16(Vg + (size_t)(32 + sr) * LL + g8, kb + 6144);
  }

  for (int yt = 0; yt < 32; ++yt) {
    const int cur = yt & 1;
    __syncthreads();
    if (yt + 1 < 32) {
      const int y1 = (yt + 1) * 64;
      ushort* kb = &Kv[1 - cur][tid * 8];
      gload16(Kg + (size_t)(y1 + sr) * HD + g8, kb);
      gload16(Kg + (size_t)(y1 + 32 + sr) * HD + g8, kb + 2048);
      gload16(Vg + (size_t)sr * LL + y1 + g8, kb + 4096);
      gload16(Vg + (size_t)(32 + sr) * LL + y1 + g8, kb + 6144);
    }
    const ushort* Kb = &Kv[cur][0];
    const ushort* Vb = &Kv[cur][4096];

    f32x4 sacc[4][2] = {};
#pragma unroll
    for (int kk = 0; kk < 2; ++kk)
#pragma unroll
      for (int j = 0; j < 4; ++j) {
        bf16x8 bk = *(const bf16x8*)&Kb[(j * 16 + col) * 64 + (((kk * 4 + quad) ^ c7) * 8)];
        sacc[j][0] = __builtin_amdgcn_mfma_f32_16x16x32_bf16(bk, aq[0][kk], sacc[j][0], 0, 0, 0);
        sacc[j][1] = __builtin_amdgcn_mfma_f32_16x16x32_bf16(bk, aq[1][kk], sacc[j][1], 0, 0, 0);
      }
#pragma unroll
    for (int j = 0; j < 4; ++j)
#pragma unroll
      for (int i = 0; i < 2; ++i) {
        union { __hip_bfloat162 h[2]; uint2 u; } pk;
        pk.h[0] = __float22bfloat162_rn(make_float2(__expf(sacc[j][i][0] * 0.015625f),
                                                   __expf(sacc[j][i][1] * 0.015625f)));
        pk.h[1] = __float22bfloat162_rn(make_float2(__expf(sacc[j][i][2] * 0.015625f),
                                                   __expf(sacc[j][i][3] * 0.015625f)));
        *(uint2*)&Ps[(wx + i * 16 + col) * 88 + j * 16 + quad * 4] = pk.u;
      }
#pragma unroll
    for (int kk = 0; kk < 2; ++kk) {
      bf16x8 ap0 = *(const bf16x8*)&Ps[(wx + col) * 88 + kk * 32 + quad * 8];
      bf16x8 ap1 = *(const bf16x8*)&Ps[(wx + 16 + col) * 88 + kk * 32 + quad * 8];
      dacc[0] = __builtin_amdgcn_mfma_f32_16x16x32_bf16(ap0, ones, dacc[0], 0, 0, 0);
      dacc[1] = __builtin_amdgcn_mfma_f32_16x16x32_bf16(ap1, ones, dacc[1], 0, 0, 0);
#pragma unroll
      for (int j = 0; j < 4; ++j) {
        bf16x8 bv = *(const bf16x8*)&Vb[(j * 16 + col) * 64 + (((kk * 4 + quad) ^ c7) * 8)];
        oacc[0][j] = __builtin_amdgcn_mfma_f32_16x16x32_bf16(ap0, bv, oacc[0][j], 0, 0, 0);
        oacc[1][j] = __builtin_amdgcn_mfma_f32_16x16x32_bf16(ap1, bv, oacc[1][j], 0, 0, 0);
      }
    }
  }

#pragma unroll
  for (int i = 0; i < 2; ++i) {
#pragma unroll
    for (int r = 0; r < 4; ++r) {
      const int xg = x0 + wx + i * 16 + quad * 4 + r;
      const float inv = 1.f / dacc[i][r];
#pragma unroll
      for (int j = 0; j < 4; ++j) {
        const int d = j * 16 + col;
        const int flat = xg * 512 + h * 64 + d;
        const int c = flat >> 11, l = flat & 2047;
        ob[(size_t)(l + 1) * CC + c] = f2bf(oacc[i][j][r] * inv);
      }
    }
  }
  if ((slot & 15) == 0 && tid < 128) {
    const int rw = tid >> 6;
    const int cc = h * 64 + (tid & 63);
    ob[(size_t)(rw ? (LPAD - 1) : 0) * CC + cc] = 0;
  }
}

// ---------------------------------------------------------------------------
extern "C" void kernel_launch(void* const* d_in, const int* in_sizes, int n_in,
                              void* d_out, int out_size, void* d_ws, size_t ws_size,
                              hipStream_t stream) {
  const float* q    = (const float*)d_in[0];
  const float* k    = (const float*)d_in[1];
  const float* v    = (const float*)d_in[2];
  const float* wq_w = (const float*)d_in[3];
  const float* wq_b = (const float*)d_in[4];
  const float* wk_w = (const float*)d_in[5];
  const float* wk_b = (const float*)d_in[6];
  const float* wv_w = (const float*)d_in[7];
  const float* wv_b = (const float*)d_in[8];
  const float* fc_w = (const float*)d_in[9];
  const float* fc_b = (const float*)d_in[10];

  char* ws = (char*)d_ws;
  const size_t WSZ = (size_t)CC * KK * sizeof(ushort);            // 1.5 MB per conv
  const size_t HSZ = (size_t)BB * NH * LL * HD * sizeof(ushort);  // 8.39 MB per head tensor
  const size_t XSZ = (size_t)BB * LPAD * CC * sizeof(ushort);     // 8.40 MB padded xT
  const size_t FUSED_NEED = 4 * WSZ + 3 * HSZ + 3 * XSZ;          // ~56.65 MB

  ushort* Wt = (ushort*)(ws);
  prep_w<<<(4 * CC * KK + 255) / 256, 256, 0, stream>>>(wq_w, wk_w, wv_w, fc_w, Wt);

  if (ws_size >= FUSED_NEED) {
    ushort* qh  = (ushort*)(ws + 4 * WSZ);
    ushort* kh  = (ushort*)(ws + 4 * WSZ + HSZ);
    ushort* vt  = (ushort*)(ws + 4 * WSZ + 2 * HSZ);
    ushort* xTq = (ushort*)(ws + 4 * WSZ + 3 * HSZ);
    ushort* xTk = (ushort*)(ws + 4 * WSZ + 3 * HSZ + XSZ);
    ushort* xTv = (ushort*)(ws + 4 * WSZ + 3 * HSZ + 2 * XSZ);
    ushort* obT = xTq;                  // attn output (xTq dead after conv3)
    // attn split-combine scratch, all in regions dead after conv3 / pre-fc:
    ushort* Pp  = xTk;                                  // 16 MB bf16 partials
    int*    cnt = (int*)((char*)xTk + 16777216);        // 2 KB counters (inside xTk∪xTv)
    float*  Dp  = (float*)d_out;                        // 512 KB denoms (fc overwrites)

    transpose3_k<<<dim3(32, 8, 12), 256, 0, stream>>>(q, k, v, xTq, xTk, xTv);
    conv3_k<<<dim3(16, 4, 12), 256, 0, stream>>>(xTq, xTk, xTv, Wt,
                                                 wq_b, wk_b, wv_b, qh, kh, vt);
    hipMemsetAsync(cnt, 0, 2048, stream);   // after conv3 (xTk dead), before attn
    attn_k<<<1024, 256, 0, stream>>>(qh, kh, vt, Pp, Dp, cnt, obT);
    conv_k<<<dim3(16, 4, 4), 256, 0, stream>>>(obT, Wt + 3 * CC * KK, fc_b,
                                               (float*)d_out, 2);
  } else {
    ushort* qh  = (ushort*)(ws + 4 * WSZ);
    ushort* kh  = (ushort*)(ws + 4 * WSZ + HSZ);
    ushort* vt  = (ushort*)(ws + 4 * WSZ + 2 * HSZ);
    ushort* xTb = (ushort*)(ws + 4 * WSZ + 3 * HSZ);
    ushort* obT = xTb;

    transpose_k<<<dim3(32, 8, 4), 256, 0, stream>>>(q, xTb);
    conv_k<<<dim3(16, 4, 4), 256, 0, stream>>>(xTb, Wt + 0 * CC * KK, wq_b, qh, 0);
    transpose_k<<<dim3(32, 8, 4), 256, 0, stream>>>(k, xTb);
    conv_k<<<dim3(16, 4, 4), 256, 0, stream>>>(xTb, Wt + 1 * CC * KK, wk_b, kh, 0);
    transpose_k<<<dim3(32, 8, 4), 256, 0, stream>>>(v, xTb);
    conv_k<<<dim3(16, 4, 4), 256, 0, stream>>>(xTb, Wt + 2 * CC * KK, wv_b, vt, 1);
    attn1_k<<<512, 256, 0, stream>>>(qh, kh, vt, obT);
    conv_k<<<dim3(16, 4, 4), 256, 0, stream>>>(obT, Wt + 3 * CC * KK, fc_b,
                                               (float*)d_out, 2);
  }
}

// Round 9
// 262.234 us; speedup vs baseline: 1.7949x; 1.7949x over previous
//
#include <hip/hip_runtime.h>
#include <hip/hip_bf16.h>

#define BB 4
#define NH 8
#define HD 64
#define CC 512
#define LL 2048
#define KK 1536   // C*3, K index = t*512 + ci
#define LPAD 2050 // padded rows of xT: row 0 and row 2049 are zeros

typedef float f32x4 __attribute__((ext_vector_type(4)));
typedef short bf16x8 __attribute__((ext_vector_type(8)));

static __device__ __forceinline__ ushort f2bf(float f) {
  union { float f; unsigned u; } v; v.f = f;
  unsigned r = v.u + 0x7fffu + ((v.u >> 16) & 1u);   // RNE
  return (ushort)(r >> 16);
}
static __device__ __forceinline__ void gload16(const ushort* g, ushort* l) {
  __builtin_amdgcn_global_load_lds((const __attribute__((address_space(1))) void*)g,
                                   (__attribute__((address_space(3))) void*)l, 16, 0, 0);
}

// ---------------------------------------------------------------------------
// Weight prep: W[co][ci][t] fp32 -> W'[co][t*512+ci] bf16, for all 4 convs.
// ---------------------------------------------------------------------------
__global__ void prep_w(const float* __restrict__ w0, const float* __restrict__ w1,
                       const float* __restrict__ w2, const float* __restrict__ w3,
                       ushort* __restrict__ out)
{
  int i = blockIdx.x * 256 + threadIdx.x;
  const int per = CC * KK;
  if (i >= 4 * per) return;
  int cidx = i / per;
  int rem  = i - cidx * per;
  int co   = rem / KK;
  int kk   = rem - co * KK;
  int t = kk >> 9, ci = kk & 511;
  const float* w = (cidx == 0) ? w0 : (cidx == 1) ? w1 : (cidx == 2) ? w2 : w3;
  out[i] = f2bf(w[((size_t)co * CC + ci) * 3 + t]);
}

// ---------------------------------------------------------------------------
// Transpose+cast body: xb[c][l] fp32 -> ob[l+1][c] bf16, zero halo rows.
// ---------------------------------------------------------------------------
__device__ __forceinline__ void transpose_body(const float* __restrict__ xb,
                                               ushort* __restrict__ ob)
{
  const int c0 = blockIdx.y * 64;
  const int l0 = blockIdx.x * 64;
  const int tid = threadIdx.x;
  __shared__ ushort T[64 * 72];
  {
    const int rr = tid >> 4;      // 0..15
    const int f4 = tid & 15;      // 0..15
#pragma unroll
    for (int it = 0; it < 4; ++it) {
      const int cc = rr + it * 16;
      ushort s[4];
      float4 vv = *(const float4*)(xb + (size_t)(c0 + cc) * LL + l0 + f4 * 4);
      s[0] = f2bf(vv.x); s[1] = f2bf(vv.y); s[2] = f2bf(vv.z); s[3] = f2bf(vv.w);
      *(ushort4*)&T[cc * 72 + f4 * 4] = *(ushort4*)s;
    }
  }
  __syncthreads();
  {
    const int lr = tid >> 3;     // 0..31
    const int ch = tid & 7;      // 0..7
#pragma unroll
    for (int it = 0; it < 2; ++it) {
      const int ll = lr + it * 32;
      ushort tmp[8];
#pragma unroll
      for (int e = 0; e < 8; ++e) tmp[e] = T[(ch * 8 + e) * 72 + ll];
      *(uint4*)(ob + (size_t)(l0 + ll + 1) * CC + c0 + ch * 8) = *(uint4*)tmp;
    }
  }
  if (blockIdx.x == 0 && tid < 8) {
    uint4 z4 = make_uint4(0, 0, 0, 0);
    *(uint4*)(ob + c0 + tid * 8) = z4;
  }
  if (blockIdx.x == (LL / 64 - 1) && tid >= 248) {
    uint4 z4 = make_uint4(0, 0, 0, 0);
    *(uint4*)(ob + (size_t)(LPAD - 1) * CC + c0 + (tid - 248) * 8) = z4;
  }
}

__global__ __launch_bounds__(256, 4)
void transpose_k(const float* __restrict__ in, ushort* __restrict__ outT)
{
  const int b = blockIdx.z;
  transpose_body(in + (size_t)b * CC * LL, outT + (size_t)b * (LPAD * CC));
}

__global__ __launch_bounds__(256, 4)
void transpose3_k(const float* __restrict__ q, const float* __restrict__ k,
                  const float* __restrict__ v, ushort* __restrict__ xq,
                  ushort* __restrict__ xk, ushort* __restrict__ xv)
{
  const int z = blockIdx.z;
  const int b = z & 3, var = z >> 2;
  const float* in = (var == 0) ? q : (var == 1) ? k : v;
  ushort* out = (var == 0) ? xq : (var == 1) ? xk : xv;
  transpose_body(in + (size_t)b * CC * LL, out + (size_t)b * (LPAD * CC));
}

// ---------------------------------------------------------------------------
// conv1d(k=3,same) as implicit GEMM — ROUND-6 PROVEN STRUCTURE, templated on
// BM (output-channel tile).  BM=128: qkv convs, grid (16,4,12) = 3 blocks/CU.
// BM=64: fc conv, grid (16,8,4) = 512 blocks = 2 blocks/CU (fixes the
// 1-block/CU occupancy hole the 128-tile fc had).  BK=64, single-buffer
// 2-barrier, (BM/32+4)x global_load_lds(16B)/thread, XOR chunk swizzle on the
// global fetch address, (BM/32)*4*2 MFMA/wave per iter.
// mode 0: heads [b][h][x][d] bf16 (q,k) | 1: heads-T [b][h][d][x] bf16 (v)
// mode 2: [b][co][l] fp32 (final fc)
// ---------------------------------------------------------------------------
template<int BM>
__device__ __forceinline__ void conv_body(const ushort* __restrict__ xb,
                                          const ushort* __restrict__ Wt,
                                          const float* __restrict__ bias,
                                          void* __restrict__ outp, int mode, int b)
{
  const int co0 = blockIdx.y * BM;
  const int l0  = blockIdx.x * 128;
  const int tid = threadIdx.x;
  const int lane = tid & 63;
  const int w    = tid >> 6;
  const int col  = lane & 15, quad = lane >> 4;
  constexpr int MI = BM / 32;              // i-tiles per wave

  __shared__ ushort Asl[BM * 64];
  __shared__ ushort Bsl[128 * 64];

  const int sr = tid >> 3;                 // 0..31
  const int g8 = ((tid & 7) ^ (sr & 7)) * 8;
  const ushort* ag  = Wt + (size_t)(co0 + sr) * KK + g8;
  const ushort* bg  = xb + (size_t)(l0 + sr) * CC + g8;
  ushort* alds = &Asl[tid * 8];
  ushort* blds = &Bsl[tid * 8];

  f32x4 acc[MI][4] = {};
  const int wm = (w & 1) * (BM / 2);
  const int wn = (w >> 1) * 64;
  const int c7 = col & 7;

  for (int k0 = 0; k0 < KK; k0 += 64) {
#pragma unroll
    for (int r2 = 0; r2 < MI; ++r2)
      gload16(ag + (size_t)(r2 * 32) * KK + k0, alds + r2 * 2048);
#pragma unroll
    for (int r2 = 0; r2 < 4; ++r2)
      gload16(bg + (size_t)(r2 * 32) * CC + k0, blds + r2 * 2048);
    __syncthreads();
#pragma unroll
    for (int kk = 0; kk < 2; ++kk) {
      bf16x8 af[MI], bfr[4];
#pragma unroll
      for (int i = 0; i < MI; ++i)
        af[i] = *(const bf16x8*)&Asl[(wm + i * 16 + col) * 64 + (((kk * 4 + quad) ^ c7) * 8)];
#pragma unroll
      for (int j = 0; j < 4; ++j)
        bfr[j] = *(const bf16x8*)&Bsl[(wn + j * 16 + col) * 64 + (((kk * 4 + quad) ^ c7) * 8)];
#pragma unroll
      for (int i = 0; i < MI; ++i)
#pragma unroll
        for (int j = 0; j < 4; ++j)
          acc[i][j] = __builtin_amdgcn_mfma_f32_16x16x32_bf16(af[i], bfr[j], acc[i][j], 0, 0, 0);
    }
    __syncthreads();
  }

  // epilogue: C/D layout row = quad*4+r (co), col = lane&15 (l)
#pragma unroll
  for (int i = 0; i < MI; ++i) {
#pragma unroll
    for (int r = 0; r < 4; ++r) {
      const int co = co0 + wm + i * 16 + quad * 4 + r;
      const float bi = bias[co];
#pragma unroll
      for (int j = 0; j < 4; ++j) {
        const int l = l0 + wn + j * 16 + col;
        const float y = acc[i][j][r] + bi;
        if (mode == 0) {
          const int xx = (co << 2) + (l >> 9);
          const int hh = (l >> 6) & 7;
          const int dd = l & 63;
          ((ushort*)outp)[((size_t)(b * NH + hh) * LL + xx) * HD + dd] = f2bf(y);
        } else if (mode == 1) {
          const int xx = (co << 2) + (l >> 9);
          const int hh = (l >> 6) & 7;
          const int dd = l & 63;
          ((ushort*)outp)[((size_t)(b * NH + hh) * HD + dd) * LL + xx] = f2bf(y);
        } else {
          ((float*)outp)[(size_t)(b * CC + co) * LL + l] = y;
        }
      }
    }
  }
}

template<int BM>
__global__ __launch_bounds__(256, 3)
void conv_k(const ushort* __restrict__ xT, const ushort* __restrict__ Wt,
            const float* __restrict__ bias, void* __restrict__ outp, int mode)
{
  const int b = blockIdx.z;
  conv_body<BM>(xT + (size_t)b * (LPAD * CC), Wt, bias, outp, mode, b);
}

__global__ __launch_bounds__(256, 3)
void conv3_k(const ushort* __restrict__ xq, const ushort* __restrict__ xk,
             const ushort* __restrict__ xv, const ushort* __restrict__ Wt,
             const float* __restrict__ b0, const float* __restrict__ b1,
             const float* __restrict__ b2, ushort* __restrict__ o0,
             ushort* __restrict__ o1, ushort* __restrict__ o2)
{
  const int z = blockIdx.z;
  const int b = z & 3, var = z >> 2;
  const ushort* xT = (var == 0) ? xq : (var == 1) ? xk : xv;
  const float* bias = (var == 0) ? b0 : (var == 1) ? b1 : b2;
  ushort* outp = (var == 0) ? o0 : (var == 1) ? o1 : o2;
  conv_body<128>(xT + (size_t)b * (LPAD * CC), Wt + (size_t)var * CC * KK, bias, outp,
                 (var == 2) ? 1 : 0, b);
}

// ---------------------------------------------------------------------------
// Attention v6 (ROUND-7 PROVEN, <70 us): block = 4 waves x 32 Q-rows (128
// Q-rows); each wave covers ALL y for its rows.  K/V double-buffered via
// async global_load_lds, 1 barrier per y-tile, prefetch after barrier.
// S^T = K Q^T (operand swap) so each lane's 4 acc regs are 4 consecutive y of
// P[x][y] -> packed ds_write_b64 (no conflicts).  Denominator via ones-MFMA.
// Output written directly in padded-transposed [b][l+1][c] bf16 for fc conv.
// Grid 512 decoded XCD-aware (4 whole heads per XCD, K/V L2-resident).
// ---------------------------------------------------------------------------
__global__ __launch_bounds__(256, 2)
void attn_k(const ushort* __restrict__ qh, const ushort* __restrict__ kh,
            const ushort* __restrict__ vt, ushort* __restrict__ obT)
{
  const int id   = blockIdx.x;
  const int xcd  = id & 7;
  const int slot = id >> 3;          // 0..63
  const int bh   = xcd * 4 + (slot >> 4);
  const int x0   = (slot & 15) * 128;
  const int b = bh >> 3, h = bh & 7;
  const int tid = threadIdx.x, lane = tid & 63, wv = tid >> 6;
  const int col = lane & 15, quad = lane >> 4;
  const int wx = wv * 32;            // wave-private Q rows / P rows
  const int c7 = col & 7;

  __shared__ ushort Kv[2][8192];     // [buf][ K 64x64 | V^T 64x64 ]  32 KB
  __shared__ ushort Ps[128 * 88];    // 22.5 KB  (P[x][y], stride 88)

  const ushort* Qg = qh + (size_t)bh * (LL * HD);
  const ushort* Kg = kh + (size_t)bh * (LL * HD);
  const ushort* Vg = vt + (size_t)bh * (HD * LL);
  ushort* ob = obT + (size_t)b * (LPAD * CC);

  const int sr = tid >> 3;                 // 0..31
  const int g8 = ((tid & 7) ^ (sr & 7)) * 8;

  // Q fragments (lane&15 = x-row, k = quad*8+j) — valid as A or B operand
  bf16x8 aq[2][2];
#pragma unroll
  for (int i = 0; i < 2; ++i)
#pragma unroll
    for (int kk = 0; kk < 2; ++kk)
      aq[i][kk] = *(const bf16x8*)(Qg + (size_t)(x0 + wx + i * 16 + col) * HD + kk * 32 + quad * 8);

  const short one = (short)0x3F80;  // bf16 1.0
  const bf16x8 ones = {one, one, one, one, one, one, one, one};

  f32x4 oacc[2][4] = {};
  f32x4 dacc[2] = {};

  // prefetch y-tile 0 into buf 0
  {
    ushort* kb = &Kv[0][tid * 8];
    gload16(Kg + (size_t)sr * HD + g8, kb);
    gload16(Kg + (size_t)(32 + sr) * HD + g8, kb + 2048);
    gload16(Vg + (size_t)sr * LL + g8, kb + 4096);
    gload16(Vg + (size_t)(32 + sr) * LL + g8, kb + 6144);
  }

  for (int yt = 0; yt < 32; ++yt) {
    const int cur = yt & 1;
    __syncthreads();
    if (yt + 1 < 32) {
      const int y1 = (yt + 1) * 64;
      ushort* kb = &Kv[1 - cur][tid * 8];
      gload16(Kg + (size_t)(y1 + sr) * HD + g8, kb);
      gload16(Kg + (size_t)(y1 + 32 + sr) * HD + g8, kb + 2048);
      gload16(Vg + (size_t)sr * LL + y1 + g8, kb + 4096);
      gload16(Vg + (size_t)(32 + sr) * LL + y1 + g8, kb + 6144);
    }
    const ushort* Kb = &Kv[cur][0];
    const ushort* Vb = &Kv[cur][4096];

    // S^T = K Q^T : C rows (quad*4+r) = y-local, cols = x-local
    f32x4 sacc[4][2] = {};
#pragma unroll
    for (int kk = 0; kk < 2; ++kk)
#pragma unroll
      for (int j = 0; j < 4; ++j) {
        bf16x8 bk = *(const bf16x8*)&Kb[(j * 16 + col) * 64 + (((kk * 4 + quad) ^ c7) * 8)];
        sacc[j][0] = __builtin_amdgcn_mfma_f32_16x16x32_bf16(bk, aq[0][kk], sacc[j][0], 0, 0, 0);
        sacc[j][1] = __builtin_amdgcn_mfma_f32_16x16x32_bf16(bk, aq[1][kk], sacc[j][1], 0, 0, 0);
      }
    // exp + pack 4 consecutive-y bf16 -> one ds_write_b64 per (j,i)
#pragma unroll
    for (int j = 0; j < 4; ++j)
#pragma unroll
      for (int i = 0; i < 2; ++i) {
        union { __hip_bfloat162 h[2]; uint2 u; } pk;
        pk.h[0] = __float22bfloat162_rn(make_float2(__expf(sacc[j][i][0] * 0.015625f),
                                                   __expf(sacc[j][i][1] * 0.015625f)));
        pk.h[1] = __float22bfloat162_rn(make_float2(__expf(sacc[j][i][2] * 0.015625f),
                                                   __expf(sacc[j][i][3] * 0.015625f)));
        *(uint2*)&Ps[(wx + i * 16 + col) * 88 + j * 16 + quad * 4] = pk.u;
      }
    // O += P V ; denom += P * ones
#pragma unroll
    for (int kk = 0; kk < 2; ++kk) {
      bf16x8 ap0 = *(const bf16x8*)&Ps[(wx + col) * 88 + kk * 32 + quad * 8];
      bf16x8 ap1 = *(const bf16x8*)&Ps[(wx + 16 + col) * 88 + kk * 32 + quad * 8];
      dacc[0] = __builtin_amdgcn_mfma_f32_16x16x32_bf16(ap0, ones, dacc[0], 0, 0, 0);
      dacc[1] = __builtin_amdgcn_mfma_f32_16x16x32_bf16(ap1, ones, dacc[1], 0, 0, 0);
#pragma unroll
      for (int j = 0; j < 4; ++j) {
        bf16x8 bv = *(const bf16x8*)&Vb[(j * 16 + col) * 64 + (((kk * 4 + quad) ^ c7) * 8)];
        oacc[0][j] = __builtin_amdgcn_mfma_f32_16x16x32_bf16(ap0, bv, oacc[0][j], 0, 0, 0);
        oacc[1][j] = __builtin_amdgcn_mfma_f32_16x16x32_bf16(ap1, bv, oacc[1][j], 0, 0, 0);
      }
    }
  }

  // normalize + scatter DIRECTLY to padded-transposed [b][l+1][c] bf16
#pragma unroll
  for (int i = 0; i < 2; ++i) {
#pragma unroll
    for (int r = 0; r < 4; ++r) {
      const int xg = x0 + wx + i * 16 + quad * 4 + r;
      const float inv = 1.f / dacc[i][r];
#pragma unroll
      for (int j = 0; j < 4; ++j) {
        const int d = j * 16 + col;
        const int flat = xg * 512 + h * 64 + d;
        const int c = flat >> 11, l = flat & 2047;
        ob[(size_t)(l + 1) * CC + c] = f2bf(oacc[i][j][r] * inv);
      }
    }
  }
  if ((slot & 15) == 0 && tid < 128) {
    const int rw = tid >> 6;
    const int cc = h * 64 + (tid & 63);
    ob[(size_t)(rw ? (LPAD - 1) : 0) * CC + cc] = 0;
  }
}

// ---------------------------------------------------------------------------
extern "C" void kernel_launch(void* const* d_in, const int* in_sizes, int n_in,
                              void* d_out, int out_size, void* d_ws, size_t ws_size,
                              hipStream_t stream) {
  const float* q    = (const float*)d_in[0];
  const float* k    = (const float*)d_in[1];
  const float* v    = (const float*)d_in[2];
  const float* wq_w = (const float*)d_in[3];
  const float* wq_b = (const float*)d_in[4];
  const float* wk_w = (const float*)d_in[5];
  const float* wk_b = (const float*)d_in[6];
  const float* wv_w = (const float*)d_in[7];
  const float* wv_b = (const float*)d_in[8];
  const float* fc_w = (const float*)d_in[9];
  const float* fc_b = (const float*)d_in[10];

  char* ws = (char*)d_ws;
  const size_t WSZ = (size_t)CC * KK * sizeof(ushort);            // 1.5 MB per conv
  const size_t HSZ = (size_t)BB * NH * LL * HD * sizeof(ushort);  // 8.39 MB per head tensor
  const size_t XSZ = (size_t)BB * LPAD * CC * sizeof(ushort);     // 8.40 MB padded xT
  const size_t FUSED_NEED = 4 * WSZ + 3 * HSZ + 3 * XSZ;          // ~56.65 MB

  ushort* Wt = (ushort*)(ws);
  prep_w<<<(4 * CC * KK + 255) / 256, 256, 0, stream>>>(wq_w, wk_w, wv_w, fc_w, Wt);

  if (ws_size >= FUSED_NEED) {
    ushort* qh  = (ushort*)(ws + 4 * WSZ);
    ushort* kh  = (ushort*)(ws + 4 * WSZ + HSZ);
    ushort* vt  = (ushort*)(ws + 4 * WSZ + 2 * HSZ);
    ushort* xTq = (ushort*)(ws + 4 * WSZ + 3 * HSZ);
    ushort* xTk = (ushort*)(ws + 4 * WSZ + 3 * HSZ + XSZ);
    ushort* xTv = (ushort*)(ws + 4 * WSZ + 3 * HSZ + 2 * XSZ);
    ushort* obT = xTq;                  // attn output (xTq dead after conv3)

    transpose3_k<<<dim3(32, 8, 12), 256, 0, stream>>>(q, k, v, xTq, xTk, xTv);
    conv3_k<<<dim3(16, 4, 12), 256, 0, stream>>>(xTq, xTk, xTv, Wt,
                                                 wq_b, wk_b, wv_b, qh, kh, vt);
    attn_k<<<512, 256, 0, stream>>>(qh, kh, vt, obT);
    conv_k<64><<<dim3(16, 8, 4), 256, 0, stream>>>(obT, Wt + 3 * CC * KK, fc_b,
                                                   (float*)d_out, 2);
  } else {
    ushort* qh  = (ushort*)(ws + 4 * WSZ);
    ushort* kh  = (ushort*)(ws + 4 * WSZ + HSZ);
    ushort* vt  = (ushort*)(ws + 4 * WSZ + 2 * HSZ);
    ushort* xTb = (ushort*)(ws + 4 * WSZ + 3 * HSZ);
    ushort* obT = xTb;

    transpose_k<<<dim3(32, 8, 4), 256, 0, stream>>>(q, xTb);
    conv_k<128><<<dim3(16, 4, 4), 256, 0, stream>>>(xTb, Wt + 0 * CC * KK, wq_b, qh, 0);
    transpose_k<<<dim3(32, 8, 4), 256, 0, stream>>>(k, xTb);
    conv_k<128><<<dim3(16, 4, 4), 256, 0, stream>>>(xTb, Wt + 1 * CC * KK, wk_b, kh, 0);
    transpose_k<<<dim3(32, 8, 4), 256, 0, stream>>>(v, xTb);
    conv_k<128><<<dim3(16, 4, 4), 256, 0, stream>>>(xTb, Wt + 2 * CC * KK, wv_b, vt, 1);
    attn_k<<<512, 256, 0, stream>>>(qh, kh, vt, obT);
    conv_k<64><<<dim3(16, 8, 4), 256, 0, stream>>>(obT, Wt + 3 * CC * KK, fc_b,
                                                   (float*)d_out, 2);
  }
}